// Round 4
// baseline (172.174 us; speedup 1.0000x reference)
//
#include <hip/hip_runtime.h>

#define DT 0.01f
constexpr int N = 128;
constexpr int D = 64;
constexpr int T = 16;   // n_steps (fixed by setup_inputs)

typedef float f32x4 __attribute__((ext_vector_type(4)));  // native vec for nt-store

// Blocks 0..N-1: propagate trajectory row n (64 lanes = 64 components).
// Blocks N..N+D-1: propagate impulse-response matrix row a:
//   U_0 = dt^2 I, W_0 = dt I;  W_{m+1} = W_m + dt U_m A;  U_{m+1} = U_m + dt W_{m+1}
//   with A = W^T - I. Stores transposed: UT[m][j][a] = U_m[a][j].
__global__ __launch_bounds__(64) void traj_u_kernel(
    const float* __restrict__ x0, const float* __restrict__ v0,
    const float* __restrict__ Wg, float* __restrict__ X,
    float* __restrict__ UT, float* __restrict__ traj) {
  const int j = threadIdx.x;
  float w[D];
#pragma unroll
  for (int k4 = 0; k4 < D / 4; ++k4) {
    const float4 t4 = ((const float4*)(Wg + j * D))[k4];
    w[k4 * 4 + 0] = t4.x; w[k4 * 4 + 1] = t4.y;
    w[k4 * 4 + 2] = t4.z; w[k4 * 4 + 3] = t4.w;
  }

  const int b = blockIdx.x;
  if (b < N) {
    const int n = b;
    float x = x0[n * D + j];
    float v = v0[n * D + j];
    traj[n * D + j] = x;        // frame 0 = x0
    X[n * D + j] = x;           // X[0]
    for (int t = 1; t <= T; ++t) {
      float f0 = 0.f, f1 = 0.f, f2 = 0.f, f3 = 0.f;
#pragma unroll
      for (int k = 0; k < D; k += 4) {
        f0 += __shfl(x, k + 0) * w[k + 0];
        f1 += __shfl(x, k + 1) * w[k + 1];
        f2 += __shfl(x, k + 2) * w[k + 2];
        f3 += __shfl(x, k + 3) * w[k + 3];
      }
      float f = ((f0 + f1) + (f2 + f3)) - x;   // f = -x + x W^T
      v += DT * f;
      x += DT * v;
      if (t < T) X[t * (N * D) + n * D + j] = x;
      if ((t & 3) == 0) traj[(t >> 2) * (N * D) + n * D + j] = x;
    }
  } else {
    const int a = b - N;
    float u  = (j == a) ? DT * DT : 0.0f;
    float wv = (j == a) ? DT : 0.0f;
    UT[j * D + a] = u;
    for (int m = 1; m < T; ++m) {
      float s0 = 0.f, s1 = 0.f, s2 = 0.f, s3 = 0.f;
#pragma unroll
      for (int k = 0; k < D; k += 4) {
        s0 += __shfl(u, k + 0) * w[k + 0];
        s1 += __shfl(u, k + 1) * w[k + 1];
        s2 += __shfl(u, k + 2) * w[k + 2];
        s3 += __shfl(u, k + 3) * w[k + 3];
      }
      float s = ((s0 + s1) + (s2 + s3)) - u;  // (u A)[j]
      wv += DT * s;
      u  += DT * wv;
      UT[m * (D * D) + j * D + a] = u;
    }
  }
}

// Block (n, j0/4) computes jac[n, j0..j0+3, :, :] (64 KB contiguous):
//   jac[n,j,a,b] = sum_{t=0..15} X[t,n,b] * U_{15-t}[a,j]
// Output is never re-read by the GPU -> non-temporal stores (skip L2
// write-allocate; keeps X/UT resident in L2 for the staging reads).
__global__ __launch_bounds__(256) void jac_kernel(
    const float* __restrict__ X, const float* __restrict__ UT,
    float* __restrict__ jac) {
  __shared__ float Xns[T][D];        // 4 KB : Xns[t][b]  = x_t[n][b]
  __shared__ float Ujs[T][4][D];     // 16 KB: Ujs[t][jj][a] = U_{15-t}[a][j0+jj]
  const int tid = threadIdx.x;
  const int n  = blockIdx.x >> 4;
  const int j0 = (blockIdx.x & 15) * 4;

  {  // stage Xns: 256 float4, one per thread
    const int t = tid >> 4, c4 = (tid & 15) * 4;
    *(float4*)&Xns[t][c4] = *(const float4*)&X[t * (N * D) + n * D + c4];
  }
#pragma unroll
  for (int r = 0; r < 4; ++r) {  // stage Ujs: 1024 float4, 4 per thread
    const int idx = tid + r * 256;
    const int t = idx >> 6;
    const int jj = (idx & 63) >> 4;
    const int c4 = (idx & 15) * 4;
    *(float4*)&Ujs[t][jj][c4] =
        *(const float4*)&UT[(T - 1 - t) * (D * D) + (j0 + jj) * D + c4];
  }
  __syncthreads();

  const int w = tid >> 6;                 // wave id 0..3
  const int l = tid & 63;                 // lane
  const int a0 = w * 16 + (l >> 4) * 4;   // 4 consecutive a's
  const int b0 = (l & 15) * 4;            // 4 consecutive b's

  f32x4 acc[4][4];                        // [jj][a-row]
#pragma unroll
  for (int jj = 0; jj < 4; ++jj)
#pragma unroll
    for (int r = 0; r < 4; ++r) acc[jj][r] = (f32x4)(0.f);

#pragma unroll
  for (int t = 0; t < T; ++t) {
    const f32x4 xv = *(const f32x4*)&Xns[t][b0];   // shared across the 4 j's
#pragma unroll
    for (int jj = 0; jj < 4; ++jj) {
      const f32x4 uv = *(const f32x4*)&Ujs[t][jj][a0];
      acc[jj][0] += uv.x * xv;
      acc[jj][1] += uv.y * xv;
      acc[jj][2] += uv.z * xv;
      acc[jj][3] += uv.w * xv;
    }
  }

  const int base = a0 * D + b0;
#pragma unroll
  for (int jj = 0; jj < 4; ++jj) {
    f32x4* out = (f32x4*)(jac + ((size_t)(n * D + j0 + jj)) * (D * D) + base);
    __builtin_nontemporal_store(acc[jj][0], out);
    __builtin_nontemporal_store(acc[jj][1], out + 16);   // +64 floats
    __builtin_nontemporal_store(acc[jj][2], out + 32);   // +128 floats
    __builtin_nontemporal_store(acc[jj][3], out + 48);   // +192 floats
  }
}

extern "C" void kernel_launch(void* const* d_in, const int* in_sizes, int n_in,
                              void* d_out, int out_size, void* d_ws, size_t ws_size,
                              hipStream_t stream) {
  const float* x0 = (const float*)d_in[0];
  const float* v0 = (const float*)d_in[1];
  const float* W  = (const float*)d_in[2];
  // d_in[3] = n_steps (16), d_in[4] = store_every (4) — fixed by setup_inputs.

  float* traj = (float*)d_out;                    // 5 * 128 * 64 floats
  float* jac  = (float*)d_out + 5 * N * D;        // 128*64*64*64 floats

  float* X  = (float*)d_ws;                       // [16][128][64]
  float* UT = X + T * N * D;                      // [16][64][64] (transposed U)

  traj_u_kernel<<<dim3(N + D), dim3(64), 0, stream>>>(x0, v0, W, X, UT, traj);
  jac_kernel<<<dim3(N * D / 4), dim3(256), 0, stream>>>(X, UT, jac);
}

// Round 5
// 162.799 us; speedup vs baseline: 1.0576x; 1.0576x over previous
//
#include <hip/hip_runtime.h>

#define DT 0.01f
constexpr int N = 128;
constexpr int D = 64;
constexpr int T = 16;   // n_steps (fixed by setup_inputs)

// Blocks 0..N-1: propagate trajectory row n (64 lanes = 64 components).
// Blocks N..N+D-1: propagate impulse-response matrix row a:
//   U_0 = dt^2 I, W_0 = dt I;  W_{m+1} = W_m + dt U_m A;  U_{m+1} = U_m + dt W_{m+1}
//   with A = W^T - I  =>  jac[n,j,a,b] = sum_t X[t,n,b] * U_{15-t}[a,j].
//   Stores transposed: UT[m][j][a] = U_m[a][j] (so jac_kernel loads coalesce).
__global__ __launch_bounds__(64) void traj_u_kernel(
    const float* __restrict__ x0, const float* __restrict__ v0,
    const float* __restrict__ Wg, float* __restrict__ X,
    float* __restrict__ UT, float* __restrict__ traj) {
  const int j = threadIdx.x;
  float w[D];
#pragma unroll
  for (int k4 = 0; k4 < D / 4; ++k4) {
    const float4 t4 = ((const float4*)(Wg + j * D))[k4];
    w[k4 * 4 + 0] = t4.x; w[k4 * 4 + 1] = t4.y;
    w[k4 * 4 + 2] = t4.z; w[k4 * 4 + 3] = t4.w;
  }

  const int b = blockIdx.x;
  if (b < N) {
    const int n = b;
    float x = x0[n * D + j];
    float v = v0[n * D + j];
    traj[n * D + j] = x;        // frame 0 = x0
    X[n * D + j] = x;           // X[0]
    for (int t = 1; t <= T; ++t) {
      float f0 = 0.f, f1 = 0.f, f2 = 0.f, f3 = 0.f;
#pragma unroll
      for (int k = 0; k < D; k += 4) {
        f0 += __shfl(x, k + 0) * w[k + 0];
        f1 += __shfl(x, k + 1) * w[k + 1];
        f2 += __shfl(x, k + 2) * w[k + 2];
        f3 += __shfl(x, k + 3) * w[k + 3];
      }
      float f = ((f0 + f1) + (f2 + f3)) - x;   // f = -x + x W^T
      v += DT * f;
      x += DT * v;
      if (t < T) X[t * (N * D) + n * D + j] = x;
      if ((t & 3) == 0) traj[(t >> 2) * (N * D) + n * D + j] = x;
    }
  } else {
    const int a = b - N;
    float u  = (j == a) ? DT * DT : 0.0f;
    float wv = (j == a) ? DT : 0.0f;
    UT[j * D + a] = u;
    for (int m = 1; m < T; ++m) {
      float s0 = 0.f, s1 = 0.f, s2 = 0.f, s3 = 0.f;
#pragma unroll
      for (int k = 0; k < D; k += 4) {
        s0 += __shfl(u, k + 0) * w[k + 0];
        s1 += __shfl(u, k + 1) * w[k + 1];
        s2 += __shfl(u, k + 2) * w[k + 2];
        s3 += __shfl(u, k + 3) * w[k + 3];
      }
      float s = ((s0 + s1) + (s2 + s3)) - u;  // (u A)[j]
      wv += DT * s;
      u  += DT * wv;
      UT[m * (D * D) + j * D + a] = u;
    }
  }
}

// Block (n, j0/4) computes jac[n, j0..j0+3, :, :] (64 KB contiguous):
//   jac[n,j,a,b] = sum_{t=0..15} X[t,n,b] * U_{15-t}[a,j]
// Rank-16 outer-product accumulation. Regular (cached) float4 stores:
// measured best — nt-stores regressed 164->172 us (R4).
__global__ __launch_bounds__(256) void jac_kernel(
    const float* __restrict__ X, const float* __restrict__ UT,
    float* __restrict__ jac) {
  __shared__ float Xns[T][D];        // 4 KB : Xns[t][b]  = x_t[n][b]
  __shared__ float Ujs[T][4][D];     // 16 KB: Ujs[t][jj][a] = U_{15-t}[a][j0+jj]
  const int tid = threadIdx.x;
  const int n  = blockIdx.x >> 4;
  const int j0 = (blockIdx.x & 15) * 4;

  {  // stage Xns: 256 float4, one per thread
    const int t = tid >> 4, c4 = (tid & 15) * 4;
    *(float4*)&Xns[t][c4] = *(const float4*)&X[t * (N * D) + n * D + c4];
  }
#pragma unroll
  for (int r = 0; r < 4; ++r) {  // stage Ujs: 1024 float4, 4 per thread
    const int idx = tid + r * 256;
    const int t = idx >> 6;
    const int jj = (idx & 63) >> 4;
    const int c4 = (idx & 15) * 4;
    *(float4*)&Ujs[t][jj][c4] =
        *(const float4*)&UT[(T - 1 - t) * (D * D) + (j0 + jj) * D + c4];
  }
  __syncthreads();

  const int w = tid >> 6;                 // wave id 0..3
  const int l = tid & 63;                 // lane
  const int a0 = w * 16 + (l >> 4) * 4;   // 4 consecutive a's
  const int b0 = (l & 15) * 4;            // 4 consecutive b's

  float4 acc[4][4];                       // [jj][a-row]
#pragma unroll
  for (int jj = 0; jj < 4; ++jj)
#pragma unroll
    for (int r = 0; r < 4; ++r) acc[jj][r] = make_float4(0.f, 0.f, 0.f, 0.f);

#pragma unroll
  for (int t = 0; t < T; ++t) {
    const float4 xv = *(const float4*)&Xns[t][b0];   // shared across the 4 j's
#pragma unroll
    for (int jj = 0; jj < 4; ++jj) {
      const float4 uv = *(const float4*)&Ujs[t][jj][a0];
      acc[jj][0].x += uv.x * xv.x; acc[jj][0].y += uv.x * xv.y; acc[jj][0].z += uv.x * xv.z; acc[jj][0].w += uv.x * xv.w;
      acc[jj][1].x += uv.y * xv.x; acc[jj][1].y += uv.y * xv.y; acc[jj][1].z += uv.y * xv.z; acc[jj][1].w += uv.y * xv.w;
      acc[jj][2].x += uv.z * xv.x; acc[jj][2].y += uv.z * xv.y; acc[jj][2].z += uv.z * xv.z; acc[jj][2].w += uv.z * xv.w;
      acc[jj][3].x += uv.w * xv.x; acc[jj][3].y += uv.w * xv.y; acc[jj][3].z += uv.w * xv.z; acc[jj][3].w += uv.w * xv.w;
    }
  }

  const int base = a0 * D + b0;
#pragma unroll
  for (int jj = 0; jj < 4; ++jj) {
    float* out = jac + ((size_t)(n * D + j0 + jj)) * (D * D);
    *(float4*)&out[base +   0] = acc[jj][0];
    *(float4*)&out[base +  64] = acc[jj][1];
    *(float4*)&out[base + 128] = acc[jj][2];
    *(float4*)&out[base + 192] = acc[jj][3];
  }
}

extern "C" void kernel_launch(void* const* d_in, const int* in_sizes, int n_in,
                              void* d_out, int out_size, void* d_ws, size_t ws_size,
                              hipStream_t stream) {
  const float* x0 = (const float*)d_in[0];
  const float* v0 = (const float*)d_in[1];
  const float* W  = (const float*)d_in[2];
  // d_in[3] = n_steps (16), d_in[4] = store_every (4) — fixed by setup_inputs.

  float* traj = (float*)d_out;                    // 5 * 128 * 64 floats
  float* jac  = (float*)d_out + 5 * N * D;        // 128*64*64*64 floats

  float* X  = (float*)d_ws;                       // [16][128][64]
  float* UT = X + T * N * D;                      // [16][64][64] (transposed U)

  traj_u_kernel<<<dim3(N + D), dim3(64), 0, stream>>>(x0, v0, W, X, UT, traj);
  jac_kernel<<<dim3(N * D / 4), dim3(256), 0, stream>>>(X, UT, jac);
}